// Round 4
// baseline (6175.858 us; speedup 1.0000x reference)
//
#include <hip/hip_runtime.h>
#include <math.h>

// ---------------------------------------------------------------------------
// Problem constants (ResonanceTransformer): B=16,S=512,D=512,F=2048,L=6,V=10000
// M = B*S = 8192 tokens.
// ---------------------------------------------------------------------------
#define MTOK   8192
#define DMODEL 512
#define DFF    2048
#define NLAYER 6
#define VOCAB  10000
#define VPAD   10112     // vocab padded to multiple of 128 for GEMM tiles
#define NHEAD  8
#define DHEAD  64

// prune f32-key guard band: must exceed 2*|e32-e64| (est. ~3e-5). 30x margin.
#define BAND   1.0e-3f
#define CCAP   131072    // candidate cap per matrix (expected ~10K, 13x headroom)

typedef __attribute__((ext_vector_type(8))) __bf16 bf16x8;
typedef __attribute__((ext_vector_type(4))) float  f32x4;

// ---------------------------------------------------------------------------
// ws layout (bytes) — identical to the passing round-2 base (105,448,720).
// Prune phase (before embed) overlays [0, WH_B):
//   CVAL : f64 candidates, 18 x 131072 x 8 = 18,874,368
//   CMETA: cnt[18] | below[18] at CVAL end
// Layer phase: X / Y / SH time-shared exactly as round 2.
// ---------------------------------------------------------------------------
static const size_t X_B     = 0;
static const size_t Y_B     = (size_t)MTOK * DMODEL * 4;                  // 16,777,216
static const size_t SH_B    = Y_B * 2;                                     // 33,554,432
static const size_t WH_B    = SH_B + (size_t)MTOK * DFF * 4;               // 100,663,296
static const size_t WL_B    = WH_B + (size_t)DFF * DMODEL * 2;             // 102,760,448
static const size_t HIST_B  = WL_B + (size_t)DFF * DMODEL * 2;             // 104,857,600
static const size_t STATE_B = HIST_B + (size_t)36 * 4096 * 4;              // 105,447,424
static const size_t THR_B   = STATE_B + (size_t)36 * 32;                   // 105,448,576
static const size_t WS_NEED = THR_B + 18 * 8;                              // 105,448,720
// prune-phase scratch (inside [0, WH_B))
static const size_t CVAL_B  = 0;
static const size_t CMETA_B = (size_t)18 * CCAP * 8;                       // 18,874,368

struct PState {
    double lo, hi;
    unsigned int rank;
    unsigned int pad;
    unsigned long long found;   // f32-key bits of captured order statistic
};

// ---------------------------------------------------------------------------
// bf16 split helpers (RTNE)
// ---------------------------------------------------------------------------
__device__ __forceinline__ unsigned short f2b(float f)
{
    unsigned int u = __float_as_uint(f);
    u += 0x7fffu + ((u >> 16) & 1u);
    return (unsigned short)(u >> 16);
}
__device__ __forceinline__ float b2f(unsigned short h)
{
    return __uint_as_float(((unsigned int)h) << 16);
}

__device__ __forceinline__ void gload16(const void* g, void* l)
{
    __builtin_amdgcn_global_load_lds(
        (const __attribute__((address_space(1))) unsigned int*)g,
        (__attribute__((address_space(3))) unsigned int*)l, 16, 0, 0);
}

// ---------------------------------------------------------------------------
// prune: exact f64 |etched| chain (reference numerics, unchanged since r0)
// ---------------------------------------------------------------------------
__device__ __forceinline__ double etched_abs(float wv, int i, double step, double invn)
{
    float b0 = sinf(wv * 3.14159274f);
    b0 = fminf(1.0f, fmaxf(-1.0f, b0));
    double theta = step * (double)i;
    double c = cos(theta * invn + 2.0943951023931953);
    double bl = (double)b0;
    double bloom = bl + bl * c * 1.5;
    double e = cos(bloom * 9.869604401089358)
             + bloom * bloom * 0.003183098861837907;
    return fabs(e);
}

// fast f32 key: b0 identical (same sinf), hw __cosf downstream.
// |e32 - e64| est. ~1.5e-5; guard band BAND=1e-3 gives 30x margin.
// Explicit fmaf everywhere -> deterministic codegen at every call site.
__device__ __forceinline__ float etched_abs32(float wv, int i, float inv_nm1)
{
    float b0 = sinf(wv * 3.14159274f);
    b0 = fminf(1.0f, fmaxf(-1.0f, b0));
    float c = __cosf(fmaf((float)i, inv_nm1, 2.0943951f));
    float bloom = fmaf(b0 * 1.5f, c, b0);
    float e = fmaf(bloom * bloom, 0.0031830989f, __cosf(bloom * 9.8696044f));
    return fabsf(e);
}

__device__ __forceinline__ void prune_matrix(int m, const float* ipw, const float* w1,
                                             const float* w2, const float** w, int* n)
{
    int l = m / 3, j = m % 3;
    if (j == 0)      { *w = ipw + (size_t)l * 786432;  *n = 786432;  }
    else if (j == 1) { *w = w1  + (size_t)l * 1048576; *n = 1048576; }
    else             { *w = w2  + (size_t)l * 1048576; *n = 1048576; }
}

__global__ __launch_bounds__(256) void k_prune_init(unsigned int* hist, PState* st,
                                                    unsigned int* meta)
{
    int gid = blockIdx.x * 256 + threadIdx.x;
    for (int i = gid; i < 36 * 4096; i += gridDim.x * 256) hist[i] = 0u;
    if (gid < 36) {
        meta[gid] = 0u;
        int m = gid >> 1;
        int n = (m % 3 == 0) ? 786432 : 1048576;
        st[gid].lo = 0.0;
        st[gid].hi = 1.03;                 // > max |etched32| (~1.001)
        st[gid].rank = (unsigned)(n / 4 - 1 + (gid & 1));
        st[gid].found = 0x7FF0000000000000ULL;
    }
}

// histogram pass on f32 keys computed on the fly (exact rank math on keys)
__global__ __launch_bounds__(256) void k_hist32(const float* ipw, const float* w1,
                                                const float* w2,
                                                unsigned int* hist, PState* st)
{
    int m = blockIdx.y;
    int chunk = blockIdx.x;
    const float* w; int n;
    prune_matrix(m, ipw, w1, w2, &w, &n);
    float inv_nm1 = 1.0f / (float)(n - 1);
    __shared__ unsigned int h[2][4096];
    for (int i = threadIdx.x; i < 8192; i += 256) ((unsigned int*)h)[i] = 0u;
    __syncthreads();
    double lo0 = st[2*m].lo,   hi0 = st[2*m].hi;
    double lo1 = st[2*m+1].lo, hi1 = st[2*m+1].hi;
    double sc0 = 4096.0 / (hi0 - lo0);
    double sc1 = 4096.0 / (hi1 - lo1);
    int per = (n + 63) >> 6;
    int i0 = chunk * per;
    int i1 = min(n, i0 + per);
    for (int i = i0 + (int)threadIdx.x; i < i1; i += 256) {
        double a = (double)etched_abs32(w[i], i, inv_nm1);
        if (a >= lo0 && a < hi0) {
            int bin = (int)((a - lo0) * sc0); if (bin > 4095) bin = 4095;
            atomicAdd(&h[0][bin], 1u);
        }
        if (a >= lo1 && a < hi1) {
            int bin = (int)((a - lo1) * sc1); if (bin > 4095) bin = 4095;
            atomicAdd(&h[1][bin], 1u);
        }
    }
    __syncthreads();
    for (int i = threadIdx.x; i < 4096; i += 256) {
        if (h[0][i]) atomicAdd(&hist[(size_t)(2*m) * 4096 + i], h[0][i]);
        if (h[1][i]) atomicAdd(&hist[(size_t)(2*m+1) * 4096 + i], h[1][i]);
    }
}

__global__ __launch_bounds__(256) void k_prune_select(unsigned int* hist, PState* st)
{
    int s = blockIdx.x;
    __shared__ unsigned int h[4096];
    unsigned int* gh = hist + (size_t)s * 4096;
    for (int i = threadIdx.x; i < 4096; i += 256) { h[i] = gh[i]; gh[i] = 0u; }
    __syncthreads();
    if (threadIdx.x == 0) {
        PState ps = st[s];
        unsigned int r = ps.rank;
        unsigned int acc = 0;
        int bsel = -1; unsigned int newr = 0;
        for (int bi = 0; bi < 4096; ++bi) {
            unsigned int c = h[bi];
            if (bsel < 0 && r < acc + c) { bsel = bi; newr = r - acc; }
            acc += c;
        }
        if (bsel < 0) {
            for (int bi = 4095; bi >= 0; --bi)
                if (h[bi]) { bsel = bi; newr = h[bi] - 1; break; }
            if (bsel < 0) { bsel = 0; newr = 0; }
        }
        double width = (ps.hi - ps.lo) / 4096.0;
        st[s].lo = ps.lo + width * bsel;
        st[s].hi = ps.lo + width * (bsel + 1);
        st[s].rank = newr;
    }
}

// capture min f32 key >= lo per tracker (nonneg f32 bits are order-preserving)
__global__ __launch_bounds__(256) void k_capture32(const float* ipw, const float* w1,
                                                   const float* w2, PState* st)
{
    int m = blockIdx.y;
    int chunk = blockIdx.x;
    const float* w; int n;
    prune_matrix(m, ipw, w1, w2, &w, &n);
    float inv_nm1 = 1.0f / (float)(n - 1);
    double lo0 = st[2*m].lo, lo1 = st[2*m+1].lo;
    unsigned long long mn0 = 0x7FF0000000000000ULL, mn1 = 0x7FF0000000000000ULL;
    int per = (n + 63) >> 6;
    int i0 = chunk * per;
    int i1 = min(n, i0 + per);
    for (int i = i0 + (int)threadIdx.x; i < i1; i += 256) {
        float e = etched_abs32(w[i], i, inv_nm1);
        double a = (double)e;
        unsigned long long bits = (unsigned long long)__float_as_uint(e);
        if (a >= lo0 && bits < mn0) mn0 = bits;
        if (a >= lo1 && bits < mn1) mn1 = bits;
    }
    __shared__ unsigned long long sm[2];
    if (threadIdx.x == 0) { sm[0] = 0x7FF0000000000000ULL; sm[1] = 0x7FF0000000000000ULL; }
    __syncthreads();
    atomicMin(&sm[0], mn0);
    atomicMin(&sm[1], mn1);
    __syncthreads();
    if (threadIdx.x == 0) {
        atomicMin(&st[2*m].found, sm[0]);
        atomicMin(&st[2*m+1].found, sm[1]);
    }
}

// collect exact-f64 values of elements with key in [vA-BAND, vB+BAND];
// count elements strictly below the band (exact below-rank B).
__global__ __launch_bounds__(256) void k_collect(const float* ipw, const float* w1,
                                                 const float* w2, const PState* st,
                                                 unsigned int* meta, double* cval)
{
    int m = blockIdx.y;
    int chunk = blockIdx.x;
    const float* w; int n;
    prune_matrix(m, ipw, w1, w2, &w, &n);
    float inv_nm1 = 1.0f / (float)(n - 1);
    float vA = __uint_as_float((unsigned int)st[2*m].found);
    float vB = __uint_as_float((unsigned int)st[2*m+1].found);
    float bandLo = vA - BAND;
    float bandHi = vB + BAND;
    double* cv = cval + (size_t)m * CCAP;
    double step = (double)n / (double)(n - 1);
    double invn = 1.0 / (double)n;
    unsigned int loc = 0;
    int per = (n + 63) >> 6;
    int i0 = chunk * per;
    int i1 = min(n, i0 + per);
    for (int i = i0 + (int)threadIdx.x; i < i1; i += 256) {
        float e = etched_abs32(w[i], i, inv_nm1);
        if (e < bandLo) ++loc;
        else if (e <= bandHi) {
            unsigned int s = atomicAdd(&meta[m], 1u);
            if (s < CCAP) cv[s] = etched_abs(w[i], i, step, invn);
        }
    }
    __shared__ unsigned int sred[256];
    sred[threadIdx.x] = loc;
    __syncthreads();
    for (int s = 128; s; s >>= 1) {
        if (threadIdx.x < (unsigned)s) sred[threadIdx.x] += sred[threadIdx.x + s];
        __syncthreads();
    }
    if (threadIdx.x == 0) atomicAdd(&meta[18 + m], sred[0]);
}

// exact f64 order statistics at ranks k0,k0+1 among candidates -> thr
__global__ __launch_bounds__(256) void k_refine(const PState* st,
                                                const unsigned int* meta,
                                                const double* cval, double* thr)
{
    int m = blockIdx.x;
    int tid = threadIdx.x;
    int n = (m % 3 == 0) ? 786432 : 1048576;
    unsigned int C = meta[m]; if (C > CCAP) C = CCAP;
    unsigned int B = meta[18 + m];
    const double* cv = cval + (size_t)m * CCAP;
    float vA = __uint_as_float((unsigned int)st[2*m].found);
    float vB = __uint_as_float((unsigned int)st[2*m+1].found);
    double lo = (double)vA - 2.0 * (double)BAND;
    double hi = (double)vB + 2.0 * (double)BAND;
    double sc = 4096.0 / (hi - lo);

    __shared__ unsigned int h[4096];
    __shared__ double buf[4096];
    __shared__ int nbuf;
    __shared__ int bsel;
    __shared__ unsigned int accb;
    __shared__ double tsel[2];
    for (int i = tid; i < 4096; i += 256) h[i] = 0u;
    __syncthreads();
    for (unsigned int i = tid; i < C; i += 256) {
        int b = (int)((cv[i] - lo) * sc);
        b = max(0, min(4095, b));
        atomicAdd(&h[b], 1u);
    }
    __syncthreads();

    long k0 = (long)(n / 4 - 1);
    for (int t = 0; t < 2; ++t) {
        long r = k0 + t - (long)B;
        if (r < 0) r = 0;
        if (r >= (long)C) r = (long)C - 1;
        if (tid == 0) {
            unsigned int acc = 0; int bs = 4095; unsigned int ab = 0;
            for (int b = 0; b < 4096; ++b) {
                unsigned int c = h[b];
                if ((unsigned long)r < acc + c) { bs = b; ab = acc; break; }
                acc += c;
            }
            bsel = bs; accb = ab; nbuf = 0;
            tsel[t] = (double)vA;   // fail-safe default
        }
        __syncthreads();
        for (unsigned int i = tid; i < C; i += 256) {
            int b = (int)((cv[i] - lo) * sc);
            b = max(0, min(4095, b));
            if (b == bsel) {
                int s = atomicAdd(&nbuf, 1);
                if (s < 4096) buf[s] = cv[i];
            }
        }
        __syncthreads();
        int len = min(nbuf, 4096);
        long rin = r - (long)accb;
        if (rin < 0) rin = 0;
        if (rin >= len) rin = len - 1;
        for (int i = tid; i < len; i += 256) {
            double v = buf[i];
            long rk = 0;
            for (int j = 0; j < len; ++j) {
                double u = buf[j];
                if (u < v || (u == v && j < i)) ++rk;
            }
            if (rk == rin) tsel[t] = v;
        }
        __syncthreads();
    }
    if (tid == 0) thr[m] = tsel[0] + 0.75 * (tsel[1] - tsel[0]);
}

// masked bf16 hi/lo split: f32-key fast path, exact f64 recheck near T
__global__ __launch_bounds__(256) void k_mask_fast(const float* __restrict__ w,
                                                   unsigned short* __restrict__ oh,
                                                   unsigned short* __restrict__ ol,
                                                   const double* __restrict__ thr,
                                                   int m, int n)
{
    double T = thr[m];
    double tLo = T - (double)BAND;
    double tHi = T + (double)BAND;
    float inv_nm1 = 1.0f / (float)(n - 1);
    double step = (double)n / (double)(n - 1);
    double invn = 1.0 / (double)n;
    for (int i = blockIdx.x * 256 + threadIdx.x; i < n; i += gridDim.x * 256) {
        float wv = w[i];
        double a = (double)etched_abs32(wv, i, inv_nm1);
        bool keep;
        if (a > tHi) keep = true;
        else if (a < tLo) keep = false;
        else keep = etched_abs(wv, i, step, invn) > T;
        float v = keep ? wv : 0.0f;
        unsigned short h = f2b(v);
        oh[i] = h;
        ol[i] = f2b(v - b2f(h));
    }
}

// plain bf16 hi/lo split (with zero padding past n, up to total)
__global__ __launch_bounds__(256) void k_split(const float* __restrict__ w,
                                               unsigned short* __restrict__ oh,
                                               unsigned short* __restrict__ ol,
                                               int n, int total)
{
    for (int i = blockIdx.x * 256 + threadIdx.x; i < total; i += gridDim.x * 256) {
        float v = (i < n) ? w[i] : 0.0f;
        unsigned short h = f2b(v);
        oh[i] = h;
        ol[i] = f2b(v - b2f(h));
    }
}

// ---------------------------------------------------------------------------
// embedding: fp32 X + bf16 hi/lo split
// ---------------------------------------------------------------------------
__global__ __launch_bounds__(256) void k_embed(const int* __restrict__ src,
                                               const float* __restrict__ emb,
                                               const float* __restrict__ pos,
                                               float* __restrict__ x,
                                               unsigned short* __restrict__ xh,
                                               unsigned short* __restrict__ xl)
{
    int t = blockIdx.x;
    int tid = threadIdx.x;
    int v = src[t];
    int s = t & 511;
    const float* e = emb + (size_t)v * DMODEL;
    const float* p = pos + (size_t)s * DMODEL;
    size_t base = (size_t)t * DMODEL;
    float y0 = e[tid]       * 22.627416997969522f + p[tid];
    float y1 = e[tid + 256] * 22.627416997969522f + p[tid + 256];
    x[base + tid] = y0;
    x[base + tid + 256] = y1;
    unsigned short h0 = f2b(y0), h1 = f2b(y1);
    xh[base + tid] = h0;        xl[base + tid] = f2b(y0 - b2f(h0));
    xh[base + tid + 256] = h1;  xl[base + tid + 256] = f2b(y1 - b2f(h1));
}

// ---------------------------------------------------------------------------
// MFMA GEMM (bf16x3 split):  C[M,N] = A[M,K] @ B[N,K]^T + bias[N]
//   A and B both pre-split bf16 hi/lo arrays, staged via global_load_lds w=16.
//   mode 0: C fp32.  mode 1: relu then bf16 hi/lo split into CH/CL.
// 128x128 tile, 4 waves (2x2 of 64x64), BK=32, mfma_f32_16x16x32_bf16 x3.
// XCD-aware bijective block swizzle (m204) for L2 locality.
// ---------------------------------------------------------------------------
__global__ __launch_bounds__(256) void k_gemm_mfma(const unsigned short* __restrict__ AH,
                                                   const unsigned short* __restrict__ AL,
                                                   const unsigned short* __restrict__ BH,
                                                   const unsigned short* __restrict__ BL,
                                                   const float* __restrict__ bias,
                                                   float* __restrict__ C,
                                                   unsigned short* __restrict__ CH,
                                                   unsigned short* __restrict__ CL,
                                                   int M, int N, int K, int mode)
{
    __shared__ __align__(16) unsigned char LA[16384];   // AH | AL  (8 KB each)
    __shared__ __align__(16) unsigned char LB[16384];   // BH | BL
    unsigned char* LAH = LA;
    unsigned char* LAL = LA + 8192;
    unsigned char* LBH = LB;
    unsigned char* LBL = LB + 8192;

    const int t    = threadIdx.x;
    const int lane = t & 63;
    const int wv   = t >> 6;
    const int wm   = wv >> 1;
    const int wn   = wv & 1;

    // XCD-aware bijective swizzle: contiguous wg chunk per XCD
    int gx = gridDim.x;
    int wg = blockIdx.y * gx + blockIdx.x;
    int nwg = gx * gridDim.y;
    {
        int q = nwg >> 3, r = nwg & 7, xcd = wg & 7, ord = wg >> 3;
        wg = (xcd < r ? xcd * (q + 1) : r * (q + 1) + (xcd - r) * q) + ord;
    }
    const int rowBase = (wg / gx) * 128;
    const int colBase = (wg % gx) * 128;

    const f32x4 zero = {0.0f, 0.0f, 0.0f, 0.0f};
    f32x4 acc[4][4];
#pragma unroll
    for (int i = 0; i < 4; ++i)
#pragma unroll
        for (int j = 0; j < 4; ++j) acc[i][j] = zero;

    // swizzled fragment ds_read byte offsets
    int aoff[4], boff[4];
#pragma unroll
    for (int i = 0; i < 4; ++i) {
        int ra = (wm << 6) + (i << 4) + (lane & 15);
        aoff[i] = ra * 64 + (((lane >> 4) ^ ((ra >> 1) & 3)) << 4);
        int rb = (wn << 6) + (i << 4) + (lane & 15);
        boff[i] = rb * 64 + (((lane >> 4) ^ ((rb >> 1) & 3)) << 4);
    }

    // per-thread staging slots (constant across K): linear LDS, swizzled source
    int o0 = (wv << 10) + (lane << 4);
    int r0s = o0 >> 6;
    int k0s = (((o0 >> 4) & 3) ^ ((r0s >> 1) & 3)) << 3;
    int o1 = o0 + 4096;
    int r1s = o1 >> 6;
    int k1s = (((o1 >> 4) & 3) ^ ((r1s >> 1) & 3)) << 3;
    int ldsb0 = (wv << 10);
    int ldsb1 = (wv << 10) + 4096;

    for (int k0 = 0; k0 < K; k0 += 32) {
        __syncthreads();                     // prev tile fully consumed
        size_t ga0 = (size_t)(rowBase + r0s) * K + (k0 + k0s);
        size_t ga1 = (size_t)(rowBase + r1s) * K + (k0 + k1s);
        size_t gb0 = (size_t)(colBase + r0s) * K + (k0 + k0s);
        size_t gb1 = (size_t)(colBase + r1s) * K + (k0 + k1s);
        gload16(AH + ga0, LAH + ldsb0);
        gload16(AL + ga0, LAL + ldsb0);
        gload16(BH + gb0, LBH + ldsb0);
        gload16(BL + gb0, LBL + ldsb0);
        gload16(AH + ga1, LAH + ldsb1);
        gload16(AL + ga1, LAL + ldsb1);
        gload16(BH + gb1, LBH + ldsb1);
        gload16(BL + gb1, LBL + ldsb1);
        __syncthreads();                     // staging complete (vmcnt drained)

        bf16x8 ah[4], alo[4], bh[4], blo[4];
#pragma unroll
        for (int i = 0; i < 4; ++i) {
            ah[i]  = *(const bf16x8*)(LAH + aoff[i]);
            alo[i] = *(const bf16x8*)(LAL + aoff[i]);
            bh[i]  = *(const bf16x8*)(LBH + boff[i]);
            blo[i] = *(const bf16x8*)(LBL + boff[i]);
        }
#pragma unroll
        for (int i = 0; i < 4; ++i)
#pragma unroll
            for (int j = 0; j < 4; ++j) {
                acc[i][j] = __builtin_amdgcn_mfma_f32_16x16x32_bf16(alo[i], bh[j],  acc[i][j], 0, 0, 0);
                acc[i][j] = __builtin_amdgcn_mfma_f32_16x16x32_bf16(ah[i],  blo[j], acc[i][j], 0, 0, 0);
                acc[i][j] = __builtin_amdgcn_mfma_f32_16x16x32_bf16(ah[i],  bh[j],  acc[i][j], 0, 0, 0);
            }
    }

    // epilogue: C/D layout col=lane&15, row=(lane>>4)*4+reg
#pragma unroll
    for (int j = 0; j < 4; ++j) {
        int col = colBase + (wn << 6) + (j << 4) + (lane & 15);
        if (col < N) {
            float bv = bias[col];
#pragma unroll
            for (int i = 0; i < 4; ++i) {
                int row0 = rowBase + (wm << 6) + (i << 4) + ((lane >> 4) << 2);
#pragma unroll
                for (int r = 0; r < 4; ++r) {
                    float v = acc[i][j][r] + bv;
                    size_t idx = (size_t)(row0 + r) * N + col;
                    if (mode) {
                        v = fmaxf(v, 0.0f);
                        unsigned short hh = f2b(v);
                        CH[idx] = hh;
                        CL[idx] = f2b(v - b2f(hh));
                    } else {
                        C[idx] = v;
                    }
                }
            }
        }
    }
}

// ---------------------------------------------------------------------------
// flash attention v2 (fp32 compute; epilogue writes bf16 hi/lo split)
// ---------------------------------------------------------------------------
__global__ __launch_bounds__(256) void k_attn(const float* __restrict__ qkv,
                                              unsigned short* __restrict__ oh,
                                              unsigned short* __restrict__ ol)
{
    __shared__ float Qs[64][68];
    __shared__ float KP[64][68];
    __shared__ float Vs[64][64];
    __shared__ float red[64][17];
    __shared__ float mS[64], lS[64], aS[64];

    int bh = blockIdx.x;
    int b = bh >> 3, h = bh & 7;
    int qt = blockIdx.y;
    int t = threadIdx.x;
    int tx = t & 15, ty = t >> 4;
    int r0 = ty * 4, c0 = tx * 4;
    int rowq = b * 512 + qt * 64;

    size_t baseq = (size_t)rowq * 1536 + h * 64;
#pragma unroll
    for (int u = 0; u < 4; ++u) {
        int f = t + u * 256;
        int r = f >> 4;
        int d4 = (f & 15) << 2;
        float4 q4 = *(const float4*)(qkv + baseq + (size_t)r * 1536 + d4);
        Qs[d4 + 0][r] = q4.x; Qs[d4 + 1][r] = q4.y;
        Qs[d4 + 2][r] = q4.z; Qs[d4 + 3][r] = q4.w;
    }
    float O[4][4];
#pragma unroll
    for (int i = 0; i < 4; ++i)
#pragma unroll
        for (int j = 0; j < 4; ++j) O[i][j] = 0.0f;
    if (t < 64) { mS[t] = -INFINITY; lS[t] = 0.0f; }

    size_t basek = (size_t)(b * 512) * 1536 + h * 64;
    for (int kt = 0; kt < 8; ++kt) {
        __syncthreads();
#pragma unroll
        for (int u = 0; u < 4; ++u) {
            int f = t + u * 256;
            int r = f >> 4;
            int d4 = (f & 15) << 2;
            size_t g = basek + (size_t)(kt * 64 + r) * 1536 + d4;
            float4 k4 = *(const float4*)(qkv + g + 512);
            KP[d4 + 0][r] = k4.x; KP[d4 + 1][r] = k4.y;
            KP[d4 + 2][r] = k4.z; KP[d4 + 3][r] = k4.w;
            float4 v4 = *(const float4*)(qkv + g + 1024);
            *(float4*)&Vs[r][d4] = v4;
        }
        __syncthreads();
        float S[4][4];
#pragma unroll
        for (int i = 0; i < 4; ++i)
#pragma unroll
            for (int j = 0; j < 4; ++j) S[i][j] = 0.0f;
#pragma unroll 16
        for (int d = 0; d < 64; ++d) {
            float4 qa = *(const float4*)&Qs[d][r0];
            float4 kb = *(const float4*)&KP[d][c0];
            const float* qa_ = &qa.x;
            const float* kb_ = &kb.x;
#pragma unroll
            for (int i = 0; i < 4; ++i)
#pragma unroll
                for (int j = 0; j < 4; ++j)
                    S[i][j] = fmaf(qa_[i], kb_[j], S[i][j]);
        }
#pragma unroll
        for (int i = 0; i < 4; ++i) {
            float mx = fmaxf(fmaxf(S[i][0], S[i][1]), fmaxf(S[i][2], S[i][3]));
            red[r0 + i][tx] = mx * 0.125f;
        }
        __syncthreads();
        if (t < 64) {
            float m = red[t][0];
#pragma unroll
            for (int k = 1; k < 16; ++k) m = fmaxf(m, red[t][k]);
            float mo = mS[t];
            float mn = fmaxf(mo, m);
            aS[t] = __expf(mo - mn);
            mS[t] = mn;
        }
        __syncthreads();
#pragma unroll
        for (int i = 0; i < 4; ++i) {
            float mn = mS[r0 + i];
            float rs = 0.0f;
#pragma unroll
            for (int j = 0; j < 4; ++j) {
                float p = __expf(fmaf(S[i][j], 0.125f, -mn));
                S[i][j] = p;
                rs += p;
            }
            red[r0 + i][tx] = rs;
            *(float4*)&KP[r0 + i][c0] = *(float4*)S[i];
        }
        __syncthreads();
        if (t < 64) {
            float s = red[t][0];
#pragma unroll
            for (int k = 1; k < 16; ++k) s += red[t][k];
            lS[t] = lS[t] * aS[t] + s;
        }
        float pv[4][4];
#pragma unroll
        for (int i = 0; i < 4; ++i)
#pragma unroll
            for (int j = 0; j < 4; ++j) pv[i][j] = 0.0f;
#pragma unroll 4
        for (int c4 = 0; c4 < 64; c4 += 4) {
            float pr[4][4];
#pragma unroll
            for (int i = 0; i < 4; ++i)
                *(float4*)pr[i] = *(const float4*)&KP[r0 + i][c4];
#pragma unroll
            for (int cc = 0; cc < 4; ++cc) {
                float4 v = *(const float4*)&Vs[c4 + cc][c0];
                const float* v_ = &v.x;
#pragma unroll
                for (int i = 0; i < 4; ++i)
#pragma unroll
                    for (int j = 0; j < 4; ++j)
                        pv[i][j] = fmaf(pr[i][cc], v_[j], pv[i][j]);
            }
        }
#pragma unroll
        for (int i = 0; i < 4; ++i) {
            float a = aS[r0 + i];
#pragma unroll
            for (int j = 0; j < 4; ++j) O[i][j] = O[i][j] * a + pv[i][j];
        }
    }
    __syncthreads();
#pragma unroll
    for (int i = 0; i < 4; ++i) {
        float inv = 1.0f / lS[r0 + i];
        float o0 = O[i][0] * inv, o1 = O[i][1] * inv;
        float o2 = O[i][2] * inv, o3 = O[i][3] * inv;
        size_t idx = (size_t)(rowq + r0 + i) * 512 + h * 64 + c0;
        unsigned short h0 = f2b(o0), h1 = f2b(o1), h2 = f2b(o2), h3 = f2b(o3);
        uint2 hv, lv;
        hv.x = (unsigned)h0 | ((unsigned)h1 << 16);
        hv.y = (unsigned)h2 | ((unsigned)h3 << 16);
        lv.x = (unsigned)f2b(o0 - b2f(h0)) | ((unsigned)f2b(o1 - b2f(h1)) << 16);
        lv.y = (unsigned)f2b(o2 - b2f(h2)) | ((unsigned)f2b(o3 - b2f(h3)) << 16);
        *(uint2*)(oh + idx) = hv;
        *(uint2*)(ol + idx) = lv;
    }
}

// ---------------------------------------------------------------------------
// residual + layernorm: fp32 out + bf16 hi/lo split
// ---------------------------------------------------------------------------
__global__ __launch_bounds__(256) void k_ln(const float* x, const float* r,
                                            const float* __restrict__ g,
                                            const float* __restrict__ b,
                                            float* out,
                                            unsigned short* __restrict__ outh,
                                            unsigned short* __restrict__ outl)
{
    int t = blockIdx.x, tid = threadIdx.x;
    size_t base = (size_t)t * DMODEL;
    float a0 = x[base + tid]       + r[base + tid];
    float a1 = x[base + tid + 256] + r[base + tid + 256];
    float s = a0 + a1;
    float q = fmaf(a0, a0, a1 * a1);
#pragma unroll
    for (int off = 32; off; off >>= 1) {
        s += __shfl_xor(s, off, 64);
        q += __shfl_xor(q, off, 64);
    }
    __shared__ float sw[8];
    int w = tid >> 6, lane = tid & 63;
    if (lane == 0) { sw[w] = s; sw[4 + w] = q; }
    __syncthreads();
    s = sw[0] + sw[1] + sw[2] + sw[3];
    q = sw[4] + sw[5] + sw[6] + sw[7];
    float mean = s * (1.0f / 512.0f);
    float var = q * (1.0f / 512.0f) - mean * mean;
    float inv = 1.0f / sqrtf(var + 1e-5f);
    float y0 = (a0 - mean) * inv * g[tid]       + b[tid];
    float y1 = (a1 - mean) * inv * g[tid + 256] + b[tid + 256];
    out[base + tid]       = y0;
    out[base + tid + 256] = y1;
    unsigned short h0 = f2b(y0), h1 = f2b(y1);
    outh[base + tid] = h0;        outl[base + tid] = f2b(y0 - b2f(h0));
    outh[base + tid + 256] = h1;  outl[base + tid + 256] = f2b(y1 - b2f(h1));
}

// ---------------------------------------------------------------------------
// host side
// ---------------------------------------------------------------------------
static inline void launch_gemm_f32(const unsigned short* AH, const unsigned short* AL,
                                   const unsigned short* BH, const unsigned short* BL,
                                   const float* bias, float* C, int M, int N, int K,
                                   hipStream_t stream)
{
    dim3 grid((N + 127) / 128, M / 128);
    k_gemm_mfma<<<grid, 256, 0, stream>>>(AH, AL, BH, BL, bias, C, nullptr, nullptr,
                                          M, N, K, 0);
}
static inline void launch_gemm_split(const unsigned short* AH, const unsigned short* AL,
                                     const unsigned short* BH, const unsigned short* BL,
                                     const float* bias, unsigned short* CH,
                                     unsigned short* CL, int M, int N, int K,
                                     hipStream_t stream)
{
    dim3 grid((N + 127) / 128, M / 128);
    k_gemm_mfma<<<grid, 256, 0, stream>>>(AH, AL, BH, BL, bias, nullptr, CH, CL,
                                          M, N, K, 1);
}

extern "C" void kernel_launch(void* const* d_in, const int* in_sizes, int n_in,
                              void* d_out, int out_size, void* d_ws, size_t ws_size,
                              hipStream_t stream)
{
    (void)in_sizes; (void)n_in; (void)out_size;
    if (ws_size < WS_NEED) return;

    const int*   src = (const int*)  d_in[0];
    const float* emb = (const float*)d_in[1];
    const float* pos = (const float*)d_in[2];
    const float* ipw = (const float*)d_in[3];
    const float* ipb = (const float*)d_in[4];
    const float* opw = (const float*)d_in[5];
    const float* opb = (const float*)d_in[6];
    const float* ln1g = (const float*)d_in[7];
    const float* ln1b = (const float*)d_in[8];
    const float* ln2g = (const float*)d_in[9];
    const float* ln2b = (const float*)d_in[10];
    const float* w1  = (const float*)d_in[11];
    const float* bb1 = (const float*)d_in[12];
    const float* w2  = (const float*)d_in[13];
    const float* bb2 = (const float*)d_in[14];
    const float* ow  = (const float*)d_in[15];
    const float* ob  = (const float*)d_in[16];

    char* ws = (char*)d_ws;
    float* X   = (float*)(ws + X_B);
    float* Yf  = (float*)(ws + Y_B);                  // fp32 view (ff2 out)
    float* SHf = (float*)(ws + SH_B);                 // fp32 view (QKV / Z)
    // prune-phase scratch (dead after thresholds)
    double* CVAL = (double*)(ws + CVAL_B);
    unsigned int* META = (unsigned int*)(ws + CMETA_B);
    // split-pair views (bf16 hi/lo), time-shared:
    unsigned short* YS_H = (unsigned short*)(ws + Y_B);                    // attn-out / LN1 x-split
    unsigned short* YS_L = (unsigned short*)(ws + Y_B + 8388608);
    unsigned short* XS_H = (unsigned short*)(ws + SH_B + 50331648);        // LN2/embed x-split
    unsigned short* XS_L = (unsigned short*)(ws + SH_B + 58720256);
    unsigned short* FH   = (unsigned short*)(ws + SH_B);                   // ff1 split output
    unsigned short* FL   = (unsigned short*)(ws + SH_B + 33554432);
    unsigned short* OWH  = (unsigned short*)(ws + SH_B);                   // vocab splits
    unsigned short* OWL  = (unsigned short*)(ws + SH_B + (size_t)VPAD * DMODEL * 2);
    unsigned short* WH = (unsigned short*)(ws + WH_B);
    unsigned short* WL = (unsigned short*)(ws + WL_B);
    unsigned int* HIST = (unsigned int*)(ws + HIST_B);
    PState* ST = (PState*)(ws + STATE_B);
    double* THR = (double*)(ws + THR_B);
    float* OUT = (float*)d_out;

    // ---- prune thresholds: exact-rank select on f32 keys + exact f64 refine ----
    k_prune_init<<<64, 256, 0, stream>>>(HIST, ST, META);
    for (int lev = 0; lev < 3; ++lev) {
        k_hist32<<<dim3(64, 18), 256, 0, stream>>>(ipw, w1, w2, HIST, ST);
        k_prune_select<<<36, 256, 0, stream>>>(HIST, ST);
    }
    k_capture32<<<dim3(64, 18), 256, 0, stream>>>(ipw, w1, w2, ST);
    k_collect<<<dim3(64, 18), 256, 0, stream>>>(ipw, w1, w2, ST, META, CVAL);
    k_refine<<<18, 256, 0, stream>>>(ST, META, CVAL, THR);

    // ---- embedding (after prune phase frees X) ----
    k_embed<<<MTOK, 256, 0, stream>>>(src, emb, pos, X, XS_H, XS_L);

    for (int l = 0; l < NLAYER; ++l) {
        // masked in_proj split
        k_mask_fast<<<512, 256, 0, stream>>>(ipw + (size_t)l * 786432, WH, WL,
                                             THR, 3 * l, 786432);
        // qkv = x @ W^T + b  -> SHf[0..50.3MB) fp32  (A-split at SH+50.3MB)
        launch_gemm_f32(XS_H, XS_L, WH, WL, ipb + (size_t)l * 1536, SHf,
                        MTOK, 1536, DMODEL, stream);
        // attention: SHf -> split pair in Y region
        k_attn<<<dim3(128, 8), 256, 0, stream>>>(SHf, YS_H, YS_L);
        // out projection (raw weights, split): Y-split -> Z fp32 at SHf
        k_split<<<512, 256, 0, stream>>>(opw + (size_t)l * 262144, WH, WL, 262144, 262144);
        launch_gemm_f32(YS_H, YS_L, WH, WL, opb + (size_t)l * 512, SHf,
                        MTOK, DMODEL, DMODEL, stream);
        // x = LN(x + z); x-split -> Y region (Z dead after this)
        k_ln<<<MTOK, 256, 0, stream>>>(X, SHf, ln1g + (size_t)l * 512,
                                       ln1b + (size_t)l * 512, X, YS_H, YS_L);
        // masked lin1 split
        k_mask_fast<<<512, 256, 0, stream>>>(w1 + (size_t)l * 1048576, WH, WL,
                                             THR, 3 * l + 1, 1048576);
        // ff1 = relu(x @ W1^T + b) -> split pair FH|FL in SH
        launch_gemm_split(YS_H, YS_L, WH, WL, bb1 + (size_t)l * 2048, FH, FL,
                          MTOK, DFF, DMODEL, stream);
        // masked lin2 split
        k_mask_fast<<<512, 256, 0, stream>>>(w2 + (size_t)l * 1048576, WH, WL,
                                             THR, 3 * l + 2, 1048576);
        // ff2 = ff1 @ W2^T + b -> Yf fp32 (LN1 x-split dead after ff1)
        launch_gemm_f32(FH, FL, WH, WL, bb2 + (size_t)l * 512, Yf,
                        MTOK, DMODEL, DFF, stream);
        // x = LN(x + ff); x-split -> XS slot in SH (F dead)
        k_ln<<<MTOK, 256, 0, stream>>>(X, Yf, ln2g + (size_t)l * 512,
                                       ln2b + (size_t)l * 512, X, XS_H, XS_L);
    }

    // logits = x @ out_w^T + out_b  (out_w split + zero-padded to 10112 rows)
    k_split<<<2048, 256, 0, stream>>>(ow, OWH, OWL, VOCAB * DMODEL, VPAD * DMODEL);
    launch_gemm_f32(XS_H, XS_L, OWH, OWL, ob, OUT, MTOK, VOCAB, DMODEL, stream);
}

// Round 5
// 4387.271 us; speedup vs baseline: 1.4077x; 1.4077x over previous
//
#include <hip/hip_runtime.h>
#include <math.h>

// ---------------------------------------------------------------------------
// Problem constants (ResonanceTransformer): B=16,S=512,D=512,F=2048,L=6,V=10000
// M = B*S = 8192 tokens.
// ---------------------------------------------------------------------------
#define MTOK   8192
#define DMODEL 512
#define DFF    2048
#define NLAYER 6
#define VOCAB  10000
#define VPAD   10112     // vocab padded to multiple of 128 for GEMM tiles
#define NHEAD  8
#define DHEAD  64

// prune f32-key guard band: must exceed 2*|e32-e64| (est. ~3e-5). 30x margin.
#define BAND   1.0e-3f
#define CCAP   131072    // candidate cap per matrix (expected ~10-20K, 6x headroom)
#define LCAP   8192      // per-block LDS candidate list cap (expected ~360, 22x)

typedef __attribute__((ext_vector_type(8))) __bf16 bf16x8;
typedef __attribute__((ext_vector_type(4))) float  f32x4;

// ---------------------------------------------------------------------------
// ws layout (bytes) — identical to the passing round-2/4 base (105,448,720).
// Prune phase (before embed) overlays [0, WH_B):
//   CVAL : f64 candidates, 18 x 131072 x 8 = 18,874,368
//   CMETA: count/below counters, 128B-strided (36 x 32 uints)
// Layer phase: X / Y / SH time-shared exactly as round 2.
// ---------------------------------------------------------------------------
static const size_t X_B     = 0;
static const size_t Y_B     = (size_t)MTOK * DMODEL * 4;                  // 16,777,216
static const size_t SH_B    = Y_B * 2;                                     // 33,554,432
static const size_t WH_B    = SH_B + (size_t)MTOK * DFF * 4;               // 100,663,296
static const size_t WL_B    = WH_B + (size_t)DFF * DMODEL * 2;             // 102,760,448
static const size_t HIST_B  = WL_B + (size_t)DFF * DMODEL * 2;             // 104,857,600
static const size_t STATE_B = HIST_B + (size_t)36 * 4096 * 4;              // 105,447,424
static const size_t THR_B   = STATE_B + (size_t)36 * 32;                   // 105,448,576
static const size_t WS_NEED = THR_B + 18 * 8;                              // 105,448,720
// prune-phase scratch (inside [0, WH_B))
static const size_t CVAL_B  = 0;
static const size_t CMETA_B = (size_t)18 * CCAP * 8;                       // 18,874,368

struct PState {
    double lo, hi;
    unsigned int rank;
    unsigned int pad;
    unsigned long long found;   // f32-key bits of captured order statistic
};

// ---------------------------------------------------------------------------
// bf16 split helpers (RTNE)
// ---------------------------------------------------------------------------
__device__ __forceinline__ unsigned short f2b(float f)
{
    unsigned int u = __float_as_uint(f);
    u += 0x7fffu + ((u >> 16) & 1u);
    return (unsigned short)(u >> 16);
}
__device__ __forceinline__ float b2f(unsigned short h)
{
    return __uint_as_float(((unsigned int)h) << 16);
}

__device__ __forceinline__ void gload16(const void* g, void* l)
{
    __builtin_amdgcn_global_load_lds(
        (const __attribute__((address_space(1))) unsigned int*)g,
        (__attribute__((address_space(3))) unsigned int*)l, 16, 0, 0);
}

// ---------------------------------------------------------------------------
// prune: exact f64 |etched| chain (reference numerics, unchanged since r0)
// ---------------------------------------------------------------------------
__device__ __forceinline__ double etched_abs(float wv, int i, double step, double invn)
{
    float b0 = sinf(wv * 3.14159274f);
    b0 = fminf(1.0f, fmaxf(-1.0f, b0));
    double theta = step * (double)i;
    double c = cos(theta * invn + 2.0943951023931953);
    double bl = (double)b0;
    double bloom = bl + bl * c * 1.5;
    double e = cos(bloom * 9.869604401089358)
             + bloom * bloom * 0.003183098861837907;
    return fabs(e);
}

// fast f32 key: hw __sinf/__cosf. |e32 - e64| est. ~3e-5; BAND=1e-3 -> 30x margin.
// Any deterministic key works: rank arithmetic transfers to f64 exactly as long
// as the collect band covers 2*|e32-e64| (proof in r4 notes).
__device__ __forceinline__ float etched_abs32(float wv, int i, float inv_nm1)
{
    float b0 = __sinf(wv * 3.14159274f);
    b0 = fminf(1.0f, fmaxf(-1.0f, b0));
    float c = __cosf(fmaf((float)i, inv_nm1, 2.0943951f));
    float bloom = fmaf(b0 * 1.5f, c, b0);
    float e = fmaf(bloom * bloom, 0.0031830989f, __cosf(bloom * 9.8696044f));
    return fabsf(e);
}

__device__ __forceinline__ void prune_matrix(int m, const float* ipw, const float* w1,
                                             const float* w2, const float** w, int* n)
{
    int l = m / 3, j = m % 3;
    if (j == 0)      { *w = ipw + (size_t)l * 786432;  *n = 786432;  }
    else if (j == 1) { *w = w1  + (size_t)l * 1048576; *n = 1048576; }
    else             { *w = w2  + (size_t)l * 1048576; *n = 1048576; }
}

__global__ __launch_bounds__(256) void k_prune_init(unsigned int* hist, PState* st,
                                                    unsigned int* meta)
{
    int gid = blockIdx.x * 256 + threadIdx.x;
    for (int i = gid; i < 36 * 4096; i += gridDim.x * 256) hist[i] = 0u;
    for (int i = gid; i < 36 * 32; i += gridDim.x * 256) meta[i] = 0u;
    if (gid < 36) {
        int m = gid >> 1;
        int n = (m % 3 == 0) ? 786432 : 1048576;
        st[gid].lo = 0.0;
        st[gid].hi = 1.03;                 // > max |etched32| (~1.001)
        st[gid].rank = (unsigned)(n / 4 - 1 + (gid & 1));
        st[gid].found = 0x7FF0000000000000ULL;
    }
}

// histogram pass on f32 keys computed on the fly (exact rank math on keys)
__global__ __launch_bounds__(256) void k_hist32(const float* ipw, const float* w1,
                                                const float* w2,
                                                unsigned int* hist, PState* st)
{
    int m = blockIdx.y;
    int chunk = blockIdx.x;
    const float* w; int n;
    prune_matrix(m, ipw, w1, w2, &w, &n);
    float inv_nm1 = 1.0f / (float)(n - 1);
    __shared__ unsigned int h[2][4096];
    for (int i = threadIdx.x; i < 8192; i += 256) ((unsigned int*)h)[i] = 0u;
    __syncthreads();
    double lo0 = st[2*m].lo,   hi0 = st[2*m].hi;
    double lo1 = st[2*m+1].lo, hi1 = st[2*m+1].hi;
    double sc0 = 4096.0 / (hi0 - lo0);
    double sc1 = 4096.0 / (hi1 - lo1);
    int per = (n + 63) >> 6;
    int i0 = chunk * per;
    int i1 = min(n, i0 + per);
    for (int i = i0 + (int)threadIdx.x; i < i1; i += 256) {
        double a = (double)etched_abs32(w[i], i, inv_nm1);
        if (a >= lo0 && a < hi0) {
            int bin = (int)((a - lo0) * sc0); if (bin > 4095) bin = 4095;
            atomicAdd(&h[0][bin], 1u);
        }
        if (a >= lo1 && a < hi1) {
            int bin = (int)((a - lo1) * sc1); if (bin > 4095) bin = 4095;
            atomicAdd(&h[1][bin], 1u);
        }
    }
    __syncthreads();
    for (int i = threadIdx.x; i < 4096; i += 256) {
        if (h[0][i]) atomicAdd(&hist[(size_t)(2*m) * 4096 + i], h[0][i]);
        if (h[1][i]) atomicAdd(&hist[(size_t)(2*m+1) * 4096 + i], h[1][i]);
    }
}

__global__ __launch_bounds__(256) void k_prune_select(unsigned int* hist, PState* st)
{
    int s = blockIdx.x;
    __shared__ unsigned int h[4096];
    unsigned int* gh = hist + (size_t)s * 4096;
    for (int i = threadIdx.x; i < 4096; i += 256) { h[i] = gh[i]; gh[i] = 0u; }
    __syncthreads();
    if (threadIdx.x == 0) {
        PState ps = st[s];
        unsigned int r = ps.rank;
        unsigned int acc = 0;
        int bsel = -1; unsigned int newr = 0;
        for (int bi = 0; bi < 4096; ++bi) {
            unsigned int c = h[bi];
            if (bsel < 0 && r < acc + c) { bsel = bi; newr = r - acc; }
            acc += c;
        }
        if (bsel < 0) {
            for (int bi = 4095; bi >= 0; --bi)
                if (h[bi]) { bsel = bi; newr = h[bi] - 1; break; }
            if (bsel < 0) { bsel = 0; newr = 0; }
        }
        double width = (ps.hi - ps.lo) / 4096.0;
        st[s].lo = ps.lo + width * bsel;
        st[s].hi = ps.lo + width * (bsel + 1);
        st[s].rank = newr;
    }
}

// capture min f32 key >= lo per tracker (nonneg f32 bits are order-preserving)
__global__ __launch_bounds__(256) void k_capture32(const float* ipw, const float* w1,
                                                   const float* w2, PState* st)
{
    int m = blockIdx.y;
    int chunk = blockIdx.x;
    const float* w; int n;
    prune_matrix(m, ipw, w1, w2, &w, &n);
    float inv_nm1 = 1.0f / (float)(n - 1);
    double lo0 = st[2*m].lo, lo1 = st[2*m+1].lo;
    unsigned long long mn0 = 0x7FF0000000000000ULL, mn1 = 0x7FF0000000000000ULL;
    int per = (n + 63) >> 6;
    int i0 = chunk * per;
    int i1 = min(n, i0 + per);
    for (int i = i0 + (int)threadIdx.x; i < i1; i += 256) {
        float e = etched_abs32(w[i], i, inv_nm1);
        double a = (double)e;
        unsigned long long bits = (unsigned long long)__float_as_uint(e);
        if (a >= lo0 && bits < mn0) mn0 = bits;
        if (a >= lo1 && bits < mn1) mn1 = bits;
    }
    __shared__ unsigned long long sm[2];
    if (threadIdx.x == 0) { sm[0] = 0x7FF0000000000000ULL; sm[1] = 0x7FF0000000000000ULL; }
    __syncthreads();
    atomicMin(&sm[0], mn0);
    atomicMin(&sm[1], mn1);
    __syncthreads();
    if (threadIdx.x == 0) {
        atomicMin(&st[2*m].found, sm[0]);
        atomicMin(&st[2*m+1].found, sm[1]);
    }
}

// collect exact-f64 values of elements with key in [vA-BAND, vB+BAND].
// Block-aggregated: LDS index list + ONE global atomic per block (128B-strided
// counter slots) -> no same-cacheline atomic storm (r4: 1560us -> ~30us).
// Pass B densely evaluates f64 with all lanes active.
__global__ __launch_bounds__(256) void k_collect(const float* ipw, const float* w1,
                                                 const float* w2, const PState* st,
                                                 unsigned int* meta, double* cval)
{
    int m = blockIdx.y;
    int chunk = blockIdx.x;
    const float* w; int n;
    prune_matrix(m, ipw, w1, w2, &w, &n);
    float inv_nm1 = 1.0f / (float)(n - 1);
    float vA = __uint_as_float((unsigned int)st[2*m].found);
    float vB = __uint_as_float((unsigned int)st[2*m+1].found);
    float bandLo = vA - BAND;
    float bandHi = vB + BAND;
    int per = (n + 63) >> 6;
    int i0 = chunk * per;
    int i1 = min(n, i0 + per);

    __shared__ int list[LCAP];
    __shared__ unsigned int lcnt;
    __shared__ unsigned int gbase;
    __shared__ unsigned int sred[256];
    if (threadIdx.x == 0) lcnt = 0u;
    __syncthreads();

    unsigned int below = 0;
    for (int i = i0 + (int)threadIdx.x; i < i1; i += 256) {
        float e = etched_abs32(w[i], i, inv_nm1);
        if (e < bandLo) ++below;
        else if (e <= bandHi) {
            unsigned int s = atomicAdd(&lcnt, 1u);
            if (s < LCAP) list[s] = i;
        }
    }
    sred[threadIdx.x] = below;
    __syncthreads();                 // list writes + below counts visible
    for (int s = 128; s; s >>= 1) {
        if ((int)threadIdx.x < s) sred[threadIdx.x] += sred[threadIdx.x + s];
        __syncthreads();
    }
    unsigned int cnt = min(lcnt, (unsigned int)LCAP);
    if (threadIdx.x == 0) {
        gbase = atomicAdd(&meta[m * 32], cnt);          // one atomic per block
        atomicAdd(&meta[(18 + m) * 32], sred[0]);       // padded: no line sharing
    }
    __syncthreads();
    unsigned int base = gbase;
    double step = (double)n / (double)(n - 1);
    double invn = 1.0 / (double)n;
    double* cv = cval + (size_t)m * CCAP;
    for (unsigned int j = threadIdx.x; j < cnt; j += 256) {
        unsigned int s = base + j;
        if (s < CCAP) {
            int i = list[j];
            cv[s] = etched_abs(w[i], i, step, invn);    // dense: all lanes active
        }
    }
}

// exact f64 order statistics at ranks k0,k0+1 among candidates -> thr
__global__ __launch_bounds__(256) void k_refine(const PState* st,
                                                const unsigned int* meta,
                                                const double* cval, double* thr)
{
    int m = blockIdx.x;
    int tid = threadIdx.x;
    int n = (m % 3 == 0) ? 786432 : 1048576;
    unsigned int C = meta[m * 32]; if (C > CCAP) C = CCAP;
    unsigned int B = meta[(18 + m) * 32];
    const double* cv = cval + (size_t)m * CCAP;
    float vA = __uint_as_float((unsigned int)st[2*m].found);
    float vB = __uint_as_float((unsigned int)st[2*m+1].found);
    double lo = (double)vA - 2.0 * (double)BAND;
    double hi = (double)vB + 2.0 * (double)BAND;
    double sc = 4096.0 / (hi - lo);

    __shared__ unsigned int h[4096];
    __shared__ double buf[4096];
    __shared__ int nbuf;
    __shared__ int bsel;
    __shared__ unsigned int accb;
    __shared__ double tsel[2];
    for (int i = tid; i < 4096; i += 256) h[i] = 0u;
    __syncthreads();
    for (unsigned int i = tid; i < C; i += 256) {
        int b = (int)((cv[i] - lo) * sc);
        b = max(0, min(4095, b));
        atomicAdd(&h[b], 1u);
    }
    __syncthreads();

    long k0 = (long)(n / 4 - 1);
    for (int t = 0; t < 2; ++t) {
        long r = k0 + t - (long)B;
        if (r < 0) r = 0;
        if (r >= (long)C) r = (long)C - 1;
        if (tid == 0) {
            unsigned int acc = 0; int bs = 4095; unsigned int ab = 0;
            for (int b = 0; b < 4096; ++b) {
                unsigned int c = h[b];
                if ((unsigned long)r < acc + c) { bs = b; ab = acc; break; }
                acc += c;
            }
            bsel = bs; accb = ab; nbuf = 0;
            tsel[t] = (double)vA;   // fail-safe default
        }
        __syncthreads();
        for (unsigned int i = tid; i < C; i += 256) {
            int b = (int)((cv[i] - lo) * sc);
            b = max(0, min(4095, b));
            if (b == bsel) {
                int s = atomicAdd(&nbuf, 1);
                if (s < 4096) buf[s] = cv[i];
            }
        }
        __syncthreads();
        int len = min(nbuf, 4096);
        long rin = r - (long)accb;
        if (rin < 0) rin = 0;
        if (rin >= len) rin = len - 1;
        for (int i = tid; i < len; i += 256) {
            double v = buf[i];
            long rk = 0;
            for (int j = 0; j < len; ++j) {
                double u = buf[j];
                if (u < v || (u == v && j < i)) ++rk;
            }
            if (rk == rin) tsel[t] = v;
        }
        __syncthreads();
    }
    if (tid == 0) thr[m] = tsel[0] + 0.75 * (tsel[1] - tsel[0]);
}

// masked bf16 hi/lo split: f32-key fast path, exact f64 recheck near T
__global__ __launch_bounds__(256) void k_mask_fast(const float* __restrict__ w,
                                                   unsigned short* __restrict__ oh,
                                                   unsigned short* __restrict__ ol,
                                                   const double* __restrict__ thr,
                                                   int m, int n)
{
    double T = thr[m];
    double tLo = T - (double)BAND;
    double tHi = T + (double)BAND;
    float inv_nm1 = 1.0f / (float)(n - 1);
    double step = (double)n / (double)(n - 1);
    double invn = 1.0 / (double)n;
    for (int i = blockIdx.x * 256 + threadIdx.x; i < n; i += gridDim.x * 256) {
        float wv = w[i];
        double a = (double)etched_abs32(wv, i, inv_nm1);
        bool keep;
        if (a > tHi) keep = true;
        else if (a < tLo) keep = false;
        else keep = etched_abs(wv, i, step, invn) > T;
        float v = keep ? wv : 0.0f;
        unsigned short h = f2b(v);
        oh[i] = h;
        ol[i] = f2b(v - b2f(h));
    }
}

// plain bf16 hi/lo split (with zero padding past n, up to total)
__global__ __launch_bounds__(256) void k_split(const float* __restrict__ w,
                                               unsigned short* __restrict__ oh,
                                               unsigned short* __restrict__ ol,
                                               int n, int total)
{
    for (int i = blockIdx.x * 256 + threadIdx.x; i < total; i += gridDim.x * 256) {
        float v = (i < n) ? w[i] : 0.0f;
        unsigned short h = f2b(v);
        oh[i] = h;
        ol[i] = f2b(v - b2f(h));
    }
}

// ---------------------------------------------------------------------------
// embedding: fp32 X + bf16 hi/lo split
// ---------------------------------------------------------------------------
__global__ __launch_bounds__(256) void k_embed(const int* __restrict__ src,
                                               const float* __restrict__ emb,
                                               const float* __restrict__ pos,
                                               float* __restrict__ x,
                                               unsigned short* __restrict__ xh,
                                               unsigned short* __restrict__ xl)
{
    int t = blockIdx.x;
    int tid = threadIdx.x;
    int v = src[t];
    int s = t & 511;
    const float* e = emb + (size_t)v * DMODEL;
    const float* p = pos + (size_t)s * DMODEL;
    size_t base = (size_t)t * DMODEL;
    float y0 = e[tid]       * 22.627416997969522f + p[tid];
    float y1 = e[tid + 256] * 22.627416997969522f + p[tid + 256];
    x[base + tid] = y0;
    x[base + tid + 256] = y1;
    unsigned short h0 = f2b(y0), h1 = f2b(y1);
    xh[base + tid] = h0;        xl[base + tid] = f2b(y0 - b2f(h0));
    xh[base + tid + 256] = h1;  xl[base + tid + 256] = f2b(y1 - b2f(h1));
}

// ---------------------------------------------------------------------------
// MFMA GEMM (bf16x3 split):  C[M,N] = A[M,K] @ B[N,K]^T + bias[N]
//   A and B both pre-split bf16 hi/lo arrays, staged via global_load_lds w=16.
//   mode 0: C fp32.  mode 1: relu then bf16 hi/lo split into CH/CL.
// 128x128 tile, 4 waves (2x2 of 64x64), BK=32, mfma_f32_16x16x32_bf16 x3.
// XCD-aware bijective block swizzle (m204) for L2 locality.
// ---------------------------------------------------------------------------
__global__ __launch_bounds__(256) void k_gemm_mfma(const unsigned short* __restrict__ AH,
                                                   const unsigned short* __restrict__ AL,
                                                   const unsigned short* __restrict__ BH,
                                                   const unsigned short* __restrict__ BL,
                                                   const float* __restrict__ bias,
                                                   float* __restrict__ C,
                                                   unsigned short* __restrict__ CH,
                                                   unsigned short* __restrict__ CL,
                                                   int M, int N, int K, int mode)
{
    __shared__ __align__(16) unsigned char LA[16384];   // AH | AL  (8 KB each)
    __shared__ __align__(16) unsigned char LB[16384];   // BH | BL
    unsigned char* LAH = LA;
    unsigned char* LAL = LA + 8192;
    unsigned char* LBH = LB;
    unsigned char* LBL = LB + 8192;

    const int t    = threadIdx.x;
    const int lane = t & 63;
    const int wv   = t >> 6;
    const int wm   = wv >> 1;
    const int wn   = wv & 1;

    // XCD-aware bijective swizzle: contiguous wg chunk per XCD
    int gx = gridDim.x;
    int wg = blockIdx.y * gx + blockIdx.x;
    int nwg = gx * gridDim.y;
    {
        int q = nwg >> 3, r = nwg & 7, xcd = wg & 7, ord = wg >> 3;
        wg = (xcd < r ? xcd * (q + 1) : r * (q + 1) + (xcd - r) * q) + ord;
    }
    const int rowBase = (wg / gx) * 128;
    const int colBase = (wg % gx) * 128;

    const f32x4 zero = {0.0f, 0.0f, 0.0f, 0.0f};
    f32x4 acc[4][4];
#pragma unroll
    for (int i = 0; i < 4; ++i)
#pragma unroll
        for (int j = 0; j < 4; ++j) acc[i][j] = zero;

    // swizzled fragment ds_read byte offsets
    int aoff[4], boff[4];
#pragma unroll
    for (int i = 0; i < 4; ++i) {
        int ra = (wm << 6) + (i << 4) + (lane & 15);
        aoff[i] = ra * 64 + (((lane >> 4) ^ ((ra >> 1) & 3)) << 4);
        int rb = (wn << 6) + (i << 4) + (lane & 15);
        boff[i] = rb * 64 + (((lane >> 4) ^ ((rb >> 1) & 3)) << 4);
    }

    // per-thread staging slots (constant across K): linear LDS, swizzled source
    int o0 = (wv << 10) + (lane << 4);
    int r0s = o0 >> 6;
    int k0s = (((o0 >> 4) & 3) ^ ((r0s >> 1) & 3)) << 3;
    int o1 = o0 + 4096;
    int r1s = o1 >> 6;
    int k1s = (((o1 >> 4) & 3) ^ ((r1s >> 1) & 3)) << 3;
    int ldsb0 = (wv << 10);
    int ldsb1 = (wv << 10) + 4096;

    for (int k0 = 0; k0 < K; k0 += 32) {
        __syncthreads();                     // prev tile fully consumed
        size_t ga0 = (size_t)(rowBase + r0s) * K + (k0 + k0s);
        size_t ga1 = (size_t)(rowBase + r1s) * K + (k0 + k1s);
        size_t gb0 = (size_t)(colBase + r0s) * K + (k0 + k0s);
        size_t gb1 = (size_t)(colBase + r1s) * K + (k0 + k1s);
        gload16(AH + ga0, LAH + ldsb0);
        gload16(AL + ga0, LAL + ldsb0);
        gload16(BH + gb0, LBH + ldsb0);
        gload16(BL + gb0, LBL + ldsb0);
        gload16(AH + ga1, LAH + ldsb1);
        gload16(AL + ga1, LAL + ldsb1);
        gload16(BH + gb1, LBH + ldsb1);
        gload16(BL + gb1, LBL + ldsb1);
        __syncthreads();                     // staging complete (vmcnt drained)

        bf16x8 ah[4], alo[4], bh[4], blo[4];
#pragma unroll
        for (int i = 0; i < 4; ++i) {
            ah[i]  = *(const bf16x8*)(LAH + aoff[i]);
            alo[i] = *(const bf16x8*)(LAL + aoff[i]);
            bh[i]  = *(const bf16x8*)(LBH + boff[i]);
            blo[i] = *(const bf16x8*)(LBL + boff[i]);
        }
#pragma unroll
        for (int i = 0; i < 4; ++i)
#pragma unroll
            for (int j = 0; j < 4; ++j) {
                acc[i][j] = __builtin_amdgcn_mfma_f32_16x16x32_bf16(alo[i], bh[j],  acc[i][j], 0, 0, 0);
                acc[i][j] = __builtin_amdgcn_mfma_f32_16x16x32_bf16(ah[i],  blo[j], acc[i][j], 0, 0, 0);
                acc[i][j] = __builtin_amdgcn_mfma_f32_16x16x32_bf16(ah[i],  bh[j],  acc[i][j], 0, 0, 0);
            }
    }

    // epilogue: C/D layout col=lane&15, row=(lane>>4)*4+reg
#pragma unroll
    for (int j = 0; j < 4; ++j) {
        int col = colBase + (wn << 6) + (j << 4) + (lane & 15);
        if (col < N) {
            float bv = bias[col];
#pragma unroll
            for (int i = 0; i < 4; ++i) {
                int row0 = rowBase + (wm << 6) + (i << 4) + ((lane >> 4) << 2);
#pragma unroll
                for (int r = 0; r < 4; ++r) {
                    float v = acc[i][j][r] + bv;
                    size_t idx = (size_t)(row0 + r) * N + col;
                    if (mode) {
                        v = fmaxf(v, 0.0f);
                        unsigned short hh = f2b(v);
                        CH[idx] = hh;
                        CL[idx] = f2b(v - b2f(hh));
                    } else {
                        C[idx] = v;
                    }
                }
            }
        }
    }
}

// ---------------------------------------------------------------------------
// flash attention v2 (fp32 compute; epilogue writes bf16 hi/lo split)
// ---------------------------------------------------------------------------
__global__ __launch_bounds__(256) void k_attn(const float* __restrict__ qkv,
                                              unsigned short* __restrict__ oh,
                                              unsigned short* __restrict__ ol)
{
    __shared__ float Qs[64][68];
    __shared__ float KP[64][68];
    __shared__ float Vs[64][64];
    __shared__ float red[64][17];
    __shared__ float mS[64], lS[64], aS[64];

    int bh = blockIdx.x;
    int b = bh >> 3, h = bh & 7;
    int qt = blockIdx.y;
    int t = threadIdx.x;
    int tx = t & 15, ty = t >> 4;
    int r0 = ty * 4, c0 = tx * 4;
    int rowq = b * 512 + qt * 64;

    size_t baseq = (size_t)rowq * 1536 + h * 64;
#pragma unroll
    for (int u = 0; u < 4; ++u) {
        int f = t + u * 256;
        int r = f >> 4;
        int d4 = (f & 15) << 2;
        float4 q4 = *(const float4*)(qkv + baseq + (size_t)r * 1536 + d4);
        Qs[d4 + 0][r] = q4.x; Qs[d4 + 1][r] = q4.y;
        Qs[d4 + 2][r] = q4.z; Qs[d4 + 3][r] = q4.w;
    }
    float O[4][4];
#pragma unroll
    for (int i = 0; i < 4; ++i)
#pragma unroll
        for (int j = 0; j < 4; ++j) O[i][j] = 0.0f;
    if (t < 64) { mS[t] = -INFINITY; lS[t] = 0.0f; }

    size_t basek = (size_t)(b * 512) * 1536 + h * 64;
    for (int kt = 0; kt < 8; ++kt) {
        __syncthreads();
#pragma unroll
        for (int u = 0; u < 4; ++u) {
            int f = t + u * 256;
            int r = f >> 4;
            int d4 = (f & 15) << 2;
            size_t g = basek + (size_t)(kt * 64 + r) * 1536 + d4;
            float4 k4 = *(const float4*)(qkv + g + 512);
            KP[d4 + 0][r] = k4.x; KP[d4 + 1][r] = k4.y;
            KP[d4 + 2][r] = k4.z; KP[d4 + 3][r] = k4.w;
            float4 v4 = *(const float4*)(qkv + g + 1024);
            *(float4*)&Vs[r][d4] = v4;
        }
        __syncthreads();
        float S[4][4];
#pragma unroll
        for (int i = 0; i < 4; ++i)
#pragma unroll
            for (int j = 0; j < 4; ++j) S[i][j] = 0.0f;
#pragma unroll 16
        for (int d = 0; d < 64; ++d) {
            float4 qa = *(const float4*)&Qs[d][r0];
            float4 kb = *(const float4*)&KP[d][c0];
            const float* qa_ = &qa.x;
            const float* kb_ = &kb.x;
#pragma unroll
            for (int i = 0; i < 4; ++i)
#pragma unroll
                for (int j = 0; j < 4; ++j)
                    S[i][j] = fmaf(qa_[i], kb_[j], S[i][j]);
        }
#pragma unroll
        for (int i = 0; i < 4; ++i) {
            float mx = fmaxf(fmaxf(S[i][0], S[i][1]), fmaxf(S[i][2], S[i][3]));
            red[r0 + i][tx] = mx * 0.125f;
        }
        __syncthreads();
        if (t < 64) {
            float m = red[t][0];
#pragma unroll
            for (int k = 1; k < 16; ++k) m = fmaxf(m, red[t][k]);
            float mo = mS[t];
            float mn = fmaxf(mo, m);
            aS[t] = __expf(mo - mn);
            mS[t] = mn;
        }
        __syncthreads();
#pragma unroll
        for (int i = 0; i < 4; ++i) {
            float mn = mS[r0 + i];
            float rs = 0.0f;
#pragma unroll
            for (int j = 0; j < 4; ++j) {
                float p = __expf(fmaf(S[i][j], 0.125f, -mn));
                S[i][j] = p;
                rs += p;
            }
            red[r0 + i][tx] = rs;
            *(float4*)&KP[r0 + i][c0] = *(float4*)S[i];
        }
        __syncthreads();
        if (t < 64) {
            float s = red[t][0];
#pragma unroll
            for (int k = 1; k < 16; ++k) s += red[t][k];
            lS[t] = lS[t] * aS[t] + s;
        }
        float pv[4][4];
#pragma unroll
        for (int i = 0; i < 4; ++i)
#pragma unroll
            for (int j = 0; j < 4; ++j) pv[i][j] = 0.0f;
#pragma unroll 4
        for (int c4 = 0; c4 < 64; c4 += 4) {
            float pr[4][4];
#pragma unroll
            for (int i = 0; i < 4; ++i)
                *(float4*)pr[i] = *(const float4*)&KP[r0 + i][c4];
#pragma unroll
            for (int cc = 0; cc < 4; ++cc) {
                float4 v = *(const float4*)&Vs[c4 + cc][c0];
                const float* v_ = &v.x;
#pragma unroll
                for (int i = 0; i < 4; ++i)
#pragma unroll
                    for (int j = 0; j < 4; ++j)
                        pv[i][j] = fmaf(pr[i][cc], v_[j], pv[i][j]);
            }
        }
#pragma unroll
        for (int i = 0; i < 4; ++i) {
            float a = aS[r0 + i];
#pragma unroll
            for (int j = 0; j < 4; ++j) O[i][j] = O[i][j] * a + pv[i][j];
        }
    }
    __syncthreads();
#pragma unroll
    for (int i = 0; i < 4; ++i) {
        float inv = 1.0f / lS[r0 + i];
        float o0 = O[i][0] * inv, o1 = O[i][1] * inv;
        float o2 = O[i][2] * inv, o3 = O[i][3] * inv;
        size_t idx = (size_t)(rowq + r0 + i) * 512 + h * 64 + c0;
        unsigned short h0 = f2b(o0), h1 = f2b(o1), h2 = f2b(o2), h3 = f2b(o3);
        uint2 hv, lv;
        hv.x = (unsigned)h0 | ((unsigned)h1 << 16);
        hv.y = (unsigned)h2 | ((unsigned)h3 << 16);
        lv.x = (unsigned)f2b(o0 - b2f(h0)) | ((unsigned)f2b(o1 - b2f(h1)) << 16);
        lv.y = (unsigned)f2b(o2 - b2f(h2)) | ((unsigned)f2b(o3 - b2f(h3)) << 16);
        *(uint2*)(oh + idx) = hv;
        *(uint2*)(ol + idx) = lv;
    }
}

// ---------------------------------------------------------------------------
// residual + layernorm: fp32 out + bf16 hi/lo split
// ---------------------------------------------------------------------------
__global__ __launch_bounds__(256) void k_ln(const float* x, const float* r,
                                            const float* __restrict__ g,
                                            const float* __restrict__ b,
                                            float* out,
                                            unsigned short* __restrict__ outh,
                                            unsigned short* __restrict__ outl)
{
    int t = blockIdx.x, tid = threadIdx.x;
    size_t base = (size_t)t * DMODEL;
    float a0 = x[base + tid]       + r[base + tid];
    float a1 = x[base + tid + 256] + r[base + tid + 256];
    float s = a0 + a1;
    float q = fmaf(a0, a0, a1 * a1);
#pragma unroll
    for (int off = 32; off; off >>= 1) {
        s += __shfl_xor(s, off, 64);
        q += __shfl_xor(q, off, 64);
    }
    __shared__ float sw[8];
    int w = tid >> 6, lane = tid & 63;
    if (lane == 0) { sw[w] = s; sw[4 + w] = q; }
    __syncthreads();
    s = sw[0] + sw[1] + sw[2] + sw[3];
    q = sw[4] + sw[5] + sw[6] + sw[7];
    float mean = s * (1.0f / 512.0f);
    float var = q * (1.0f / 512.0f) - mean * mean;
    float inv = 1.0f / sqrtf(var + 1e-5f);
    float y0 = (a0 - mean) * inv * g[tid]       + b[tid];
    float y1 = (a1 - mean) * inv * g[tid + 256] + b[tid + 256];
    out[base + tid]       = y0;
    out[base + tid + 256] = y1;
    unsigned short h0 = f2b(y0), h1 = f2b(y1);
    outh[base + tid] = h0;        outl[base + tid] = f2b(y0 - b2f(h0));
    outh[base + tid + 256] = h1;  outl[base + tid + 256] = f2b(y1 - b2f(h1));
}

// ---------------------------------------------------------------------------
// host side
// ---------------------------------------------------------------------------
static inline void launch_gemm_f32(const unsigned short* AH, const unsigned short* AL,
                                   const unsigned short* BH, const unsigned short* BL,
                                   const float* bias, float* C, int M, int N, int K,
                                   hipStream_t stream)
{
    dim3 grid((N + 127) / 128, M / 128);
    k_gemm_mfma<<<grid, 256, 0, stream>>>(AH, AL, BH, BL, bias, C, nullptr, nullptr,
                                          M, N, K, 0);
}
static inline void launch_gemm_split(const unsigned short* AH, const unsigned short* AL,
                                     const unsigned short* BH, const unsigned short* BL,
                                     const float* bias, unsigned short* CH,
                                     unsigned short* CL, int M, int N, int K,
                                     hipStream_t stream)
{
    dim3 grid((N + 127) / 128, M / 128);
    k_gemm_mfma<<<grid, 256, 0, stream>>>(AH, AL, BH, BL, bias, nullptr, CH, CL,
                                          M, N, K, 1);
}

extern "C" void kernel_launch(void* const* d_in, const int* in_sizes, int n_in,
                              void* d_out, int out_size, void* d_ws, size_t ws_size,
                              hipStream_t stream)
{
    (void)in_sizes; (void)n_in; (void)out_size;
    if (ws_size < WS_NEED) return;

    const int*   src = (const int*)  d_in[0];
    const float* emb = (const float*)d_in[1];
    const float* pos = (const float*)d_in[2];
    const float* ipw = (const float*)d_in[3];
    const float* ipb = (const float*)d_in[4];
    const float* opw = (const float*)d_in[5];
    const float* opb = (const float*)d_in[6];
    const float* ln1g = (const float*)d_in[7];
    const float* ln1b = (const float*)d_in[8];
    const float* ln2g = (const float*)d_in[9];
    const float* ln2b = (const float*)d_in[10];
    const float* w1  = (const float*)d_in[11];
    const float* bb1 = (const float*)d_in[12];
    const float* w2  = (const float*)d_in[13];
    const float* bb2 = (const float*)d_in[14];
    const float* ow  = (const float*)d_in[15];
    const float* ob  = (const float*)d_in[16];

    char* ws = (char*)d_ws;
    float* X   = (float*)(ws + X_B);
    float* Yf  = (float*)(ws + Y_B);                  // fp32 view (ff2 out)
    float* SHf = (float*)(ws + SH_B);                 // fp32 view (QKV / Z)
    // prune-phase scratch (dead after thresholds)
    double* CVAL = (double*)(ws + CVAL_B);
    unsigned int* META = (unsigned int*)(ws + CMETA_B);
    // split-pair views (bf16 hi/lo), time-shared:
    unsigned short* YS_H = (unsigned short*)(ws + Y_B);                    // attn-out / LN1 x-split
    unsigned short* YS_L = (unsigned short*)(ws + Y_B + 8388608);
    unsigned short* XS_H = (unsigned short*)(ws + SH_B + 50331648);        // LN2/embed x-split
    unsigned short* XS_L = (unsigned short*)(ws + SH_B + 58720256);
    unsigned short* FH   = (unsigned short*)(ws + SH_B);                   // ff1 split output
    unsigned short* FL   = (unsigned short*)(ws + SH_B + 33554432);
    unsigned short* OWH  = (unsigned short*)(ws + SH_B);                   // vocab splits
    unsigned short* OWL  = (unsigned short*)(ws + SH_B + (size_t)VPAD * DMODEL * 2);
    unsigned short* WH = (unsigned short*)(ws + WH_B);
    unsigned short* WL = (unsigned short*)(ws + WL_B);
    unsigned int* HIST = (unsigned int*)(ws + HIST_B);
    PState* ST = (PState*)(ws + STATE_B);
    double* THR = (double*)(ws + THR_B);
    float* OUT = (float*)d_out;

    // ---- prune thresholds: exact-rank select on f32 keys + exact f64 refine ----
    k_prune_init<<<64, 256, 0, stream>>>(HIST, ST, META);
    for (int lev = 0; lev < 3; ++lev) {
        k_hist32<<<dim3(64, 18), 256, 0, stream>>>(ipw, w1, w2, HIST, ST);
        k_prune_select<<<36, 256, 0, stream>>>(HIST, ST);
    }
    k_capture32<<<dim3(64, 18), 256, 0, stream>>>(ipw, w1, w2, ST);
    k_collect<<<dim3(64, 18), 256, 0, stream>>>(ipw, w1, w2, ST, META, CVAL);
    k_refine<<<18, 256, 0, stream>>>(ST, META, CVAL, THR);

    // ---- embedding (after prune phase frees X) ----
    k_embed<<<MTOK, 256, 0, stream>>>(src, emb, pos, X, XS_H, XS_L);

    for (int l = 0; l < NLAYER; ++l) {
        // masked in_proj split
        k_mask_fast<<<512, 256, 0, stream>>>(ipw + (size_t)l * 786432, WH, WL,
                                             THR, 3 * l, 786432);
        // qkv = x @ W^T + b  -> SHf[0..50.3MB) fp32  (A-split at SH+50.3MB)
        launch_gemm_f32(XS_H, XS_L, WH, WL, ipb + (size_t)l * 1536, SHf,
                        MTOK, 1536, DMODEL, stream);
        // attention: SHf -> split pair in Y region
        k_attn<<<dim3(128, 8), 256, 0, stream>>>(SHf, YS_H, YS_L);
        // out projection (raw weights, split): Y-split -> Z fp32 at SHf
        k_split<<<512, 256, 0, stream>>>(opw + (size_t)l * 262144, WH, WL, 262144, 262144);
        launch_gemm_f32(YS_H, YS_L, WH, WL, opb + (size_t)l * 512, SHf,
                        MTOK, DMODEL, DMODEL, stream);
        // x = LN(x + z); x-split -> Y region (Z dead after this)
        k_ln<<<MTOK, 256, 0, stream>>>(X, SHf, ln1g + (size_t)l * 512,
                                       ln1b + (size_t)l * 512, X, YS_H, YS_L);
        // masked lin1 split
        k_mask_fast<<<512, 256, 0, stream>>>(w1 + (size_t)l * 1048576, WH, WL,
                                             THR, 3 * l + 1, 1048576);
        // ff1 = relu(x @ W1^T + b) -> split pair FH|FL in SH
        launch_gemm_split(YS_H, YS_L, WH, WL, bb1 + (size_t)l * 2048, FH, FL,
                          MTOK, DFF, DMODEL, stream);
        // masked lin2 split
        k_mask_fast<<<512, 256, 0, stream>>>(w2 + (size_t)l * 1048576, WH, WL,
                                             THR, 3 * l + 2, 1048576);
        // ff2 = ff1 @ W2^T + b -> Yf fp32 (LN1 x-split dead after ff1)
        launch_gemm_f32(FH, FL, WH, WL, bb2 + (size_t)l * 512, Yf,
                        MTOK, DMODEL, DFF, stream);
        // x = LN(x + ff); x-split -> XS slot in SH (F dead)
        k_ln<<<MTOK, 256, 0, stream>>>(X, Yf, ln2g + (size_t)l * 512,
                                       ln2b + (size_t)l * 512, X, XS_H, XS_L);
    }

    // logits = x @ out_w^T + out_b  (out_w split + zero-padded to 10112 rows)
    k_split<<<2048, 256, 0, stream>>>(ow, OWH, OWL, VOCAB * DMODEL, VPAD * DMODEL);
    launch_gemm_f32(XS_H, XS_L, OWH, OWL, ob, OUT, MTOK, VOCAB, DMODEL, stream);
}